// Round 16
// baseline (10808.987 us; speedup 1.0000x reference)
//
#include <hip/hip_runtime.h>

#define FPS_T 1024
#define FPS_K 16
#define NW    (FPS_T / 64)   // 16 waves
#define NCELL 512            // 8x8x8 spatial grid

// FROZEN golden arithmetic (verified absmax=0 in R12..R15): f32, LLVM-DAG order
//   d = fma(dz,dz, fma(dx,dx, rn(dy*dy)))
__device__ __forceinline__ float sqd_f32dag(float ax, float ay, float az,
                                            float bx, float by, float bz) {
    const float dx = __fsub_rn(ax, bx);
    const float dy = __fsub_rn(ay, by);
    const float dz = __fsub_rn(az, bz);
    float acc = __fmul_rn(dy, dy);
    acc = __builtin_fmaf(dx, dx, acc);
    acc = __builtin_fmaf(dz, dz, acc);
    return acc;
}

// Exact top-2 merge of two ordered pairs of UNIQUE keys.
__device__ __forceinline__ void p2_merge(unsigned long long& a1, unsigned long long& a2,
                                         unsigned long long b1, unsigned long long b2) {
    const unsigned long long hi = a1 > b1 ? a1 : b1;
    const unsigned long long lo = a1 > b1 ? b1 : a1;
    const unsigned long long m2 = a2 > b2 ? a2 : b2;
    a1 = hi;
    a2 = lo > m2 ? lo : m2;
}

// Counting-sort each cloud by 8x8x8 cell id into float4 {x,y,z, bits(16383-orig)}.
__global__ __launch_bounds__(1024) void preprocess_kernel(const float* __restrict__ pos,
                                                          float4* __restrict__ pxyz,
                                                          int P) {
    const int b = blockIdx.x, t = threadIdx.x;
    const float* posb = pos + (size_t)b * P * 3;
    float4* PB = pxyz + (size_t)b * P;

    __shared__ unsigned hist[NCELL];
    __shared__ unsigned scanb[NCELL];
    __shared__ float s_red[NW][8];

    float x[FPS_K], y[FPS_K], z[FPS_K];
    float lx = 1e30f, ly = 1e30f, lz = 1e30f, hx = -1e30f, hy = -1e30f, hz = -1e30f;
#pragma unroll
    for (int k = 0; k < FPS_K; ++k) {
        const int p = k * FPS_T + t;
        x[k] = posb[p * 3 + 0]; y[k] = posb[p * 3 + 1]; z[k] = posb[p * 3 + 2];
        lx = fminf(lx, x[k]); hx = fmaxf(hx, x[k]);
        ly = fminf(ly, y[k]); hy = fmaxf(hy, y[k]);
        lz = fminf(lz, z[k]); hz = fmaxf(hz, z[k]);
    }
#pragma unroll
    for (int off = 32; off >= 1; off >>= 1) {
        lx = fminf(lx, __shfl_xor(lx, off, 64)); hx = fmaxf(hx, __shfl_xor(hx, off, 64));
        ly = fminf(ly, __shfl_xor(ly, off, 64)); hy = fmaxf(hy, __shfl_xor(hy, off, 64));
        lz = fminf(lz, __shfl_xor(lz, off, 64)); hz = fmaxf(hz, __shfl_xor(hz, off, 64));
    }
    if ((t & 63) == 0) {
        const int w = t >> 6;
        s_red[w][0] = lx; s_red[w][1] = ly; s_red[w][2] = lz;
        s_red[w][3] = hx; s_red[w][4] = hy; s_red[w][5] = hz;
    }
    if (t < NCELL) hist[t] = 0;
    __syncthreads();
    lx = s_red[0][0]; ly = s_red[0][1]; lz = s_red[0][2];
    hx = s_red[0][3]; hy = s_red[0][4]; hz = s_red[0][5];
#pragma unroll
    for (int w = 1; w < NW; ++w) {
        lx = fminf(lx, s_red[w][0]); ly = fminf(ly, s_red[w][1]); lz = fminf(lz, s_red[w][2]);
        hx = fmaxf(hx, s_red[w][3]); hy = fmaxf(hy, s_red[w][4]); hz = fmaxf(hz, s_red[w][5]);
    }
    const float ivx = 8.0f / fmaxf(hx - lx, 1e-20f);
    const float ivy = 8.0f / fmaxf(hy - ly, 1e-20f);
    const float ivz = 8.0f / fmaxf(hz - lz, 1e-20f);

    int cid[FPS_K];
#pragma unroll
    for (int k = 0; k < FPS_K; ++k) {
        int cx = (int)((x[k] - lx) * ivx); cx = cx < 0 ? 0 : (cx > 7 ? 7 : cx);
        int cy = (int)((y[k] - ly) * ivy); cy = cy < 0 ? 0 : (cy > 7 ? 7 : cy);
        int cz = (int)((z[k] - lz) * ivz); cz = cz < 0 ? 0 : (cz > 7 ? 7 : cz);
        cid[k] = (cx << 6) | (cy << 3) | cz;
        atomicAdd(&hist[cid[k]], 1u);
    }
    __syncthreads();
    if (t < NCELL) scanb[t] = hist[t];
    __syncthreads();
    for (int off = 1; off < NCELL; off <<= 1) {
        unsigned add = 0;
        if (t < NCELL && t >= off) add = scanb[t - off];
        __syncthreads();
        if (t < NCELL) scanb[t] += add;
        __syncthreads();
    }
    if (t < NCELL) hist[t] = scanb[t] - hist[t];
    __syncthreads();
#pragma unroll
    for (int k = 0; k < FPS_K; ++k) {
        const int p = k * FPS_T + t;
        const unsigned dst = atomicAdd(&hist[cid[k]], 1u);
        PB[dst] = make_float4(x[k], y[k], z[k], __uint_as_float((unsigned)(16383 - p)));
    }
}

__global__ __launch_bounds__(1024) void fps_kernel(const float* __restrict__ pos,
                                                   const float4* __restrict__ pxyz,
                                                   int* __restrict__ idx_out,
                                                   int P, int M) {
#pragma clang fp contract(off)
    const int b = blockIdx.x, t = threadIdx.x;
    const float* posb = pos + (size_t)b * P * 3;
    const float4* PB = pxyz + (size_t)b * P;

    __shared__ ulonglong2 s_pair[2][NW];

    // Thread owns 16 consecutive sorted points; coords/md/tags/bbox in registers.
    float px[FPS_K], py[FPS_K], pz[FPS_K], md[FPS_K];
    unsigned tlp[FPS_K / 2];
    const int sp0 = t * FPS_K;
#pragma unroll
    for (int k = 0; k < FPS_K; ++k) {
        const float4 v = PB[sp0 + k];
        px[k] = v.x; py[k] = v.y; pz[k] = v.z;
        const unsigned tor = __float_as_uint(v.w);
        if ((k & 1) == 0) tlp[k >> 1] = tor; else tlp[k >> 1] |= tor << 16;
        md[k] = __builtin_inff();
    }
    float blx = px[0], bhx = px[0], bly = py[0], bhy = py[0], blz = pz[0], bhz = pz[0];
#pragma unroll
    for (int k = 1; k < FPS_K; ++k) {
        blx = fminf(blx, px[k]); bhx = fmaxf(bhx, px[k]);
        bly = fminf(bly, py[k]); bhy = fmaxf(bhy, py[k]);
        blz = fminf(blz, pz[k]); bhz = fmaxf(bhz, pz[k]);
    }
    if (t == 0) idx_out[(size_t)b * M] = 0;

    float s1x = posb[0], s1y = posb[1], s1z = posb[2];
    float s2x = 0.f, s2y = 0.f, s2z = 0.f;
    bool have2 = false;
    unsigned long long ck1 = 0ull, ck2 = 0ull, wk1 = 0ull, wk2 = 0ull;
    float thresh = __builtin_inff();
    int m = 1, buf = 0;

    while (m < M) {
        // ---- bbox skip vs current updating set {s1} or {s1,s2} ----
        float cx = fminf(fmaxf(s1x, blx), bhx);
        float cy = fminf(fmaxf(s1y, bly), bhy);
        float cz = fminf(fmaxf(s1z, blz), bhz);
        bool act = sqd_f32dag(cx, cy, cz, s1x, s1y, s1z) < thresh;
        if (have2) {
            cx = fminf(fmaxf(s2x, blx), bhx);
            cy = fminf(fmaxf(s2y, bly), bhy);
            cz = fminf(fmaxf(s2z, blz), bhz);
            act = act || (sqd_f32dag(cx, cy, cz, s2x, s2y, s2z) < thresh);
        }
        if (__ballot(act) != 0ull) {
            if (act) {
                unsigned long long bk1 = 0ull, bk2 = 0ull;
                if (have2) {
#pragma unroll
                    for (int k = 0; k < FPS_K; ++k) {
                        const float d1 = sqd_f32dag(px[k], py[k], pz[k], s1x, s1y, s1z);
                        const float d2 = sqd_f32dag(px[k], py[k], pz[k], s2x, s2y, s2z);
                        const float nm = fminf(fminf(md[k], d1), d2);   // min assoc: exact
                        md[k] = nm;
                        const unsigned tor = (tlp[k >> 1] >> ((k & 1) * 16)) & 0xFFFFu;
                        const unsigned long long kk =
                            ((unsigned long long)__float_as_uint(nm) << 32)
                            | (unsigned long long)((tor << 14) | (unsigned)(sp0 + k));
                        if (kk > bk1) { bk2 = bk1; bk1 = kk; }
                        else if (kk > bk2) { bk2 = kk; }
                    }
                } else {
#pragma unroll
                    for (int k = 0; k < FPS_K; ++k) {
                        const float d1 = sqd_f32dag(px[k], py[k], pz[k], s1x, s1y, s1z);
                        const float nm = fminf(md[k], d1);
                        md[k] = nm;
                        const unsigned tor = (tlp[k >> 1] >> ((k & 1) * 16)) & 0xFFFFu;
                        const unsigned long long kk =
                            ((unsigned long long)__float_as_uint(nm) << 32)
                            | (unsigned long long)((tor << 14) | (unsigned)(sp0 + k));
                        if (kk > bk1) { bk2 = bk1; bk1 = kk; }
                        else if (kk > bk2) { bk2 = kk; }
                    }
                }
                ck1 = bk1; ck2 = bk2;
                thresh = __uint_as_float((unsigned)(bk1 >> 32)) * 1.00006104f; // *(1+2^-14)
            }
            unsigned long long k1 = ck1, k2 = ck2;
#pragma unroll
            for (int off = 32; off >= 1; off >>= 1) {
                const unsigned long long o1 = __shfl_xor(k1, off, 64);
                const unsigned long long o2 = __shfl_xor(k2, off, 64);
                p2_merge(k1, k2, o1, o2);
            }
            wk1 = k1; wk2 = k2;   // cached while wave fully skips (md only decreases)
        }
        if ((t & 63) == 0) s_pair[buf][t >> 6] = make_ulonglong2(wk1, wk2);
        __syncthreads();
        // ---- width-16 cross-wave top-2 tree ----
        const ulonglong2 pr = s_pair[buf][t & (NW - 1)];
        unsigned long long g1 = pr.x, g2 = pr.y;
#pragma unroll
        for (int off = NW / 2; off >= 1; off >>= 1) {
            const unsigned long long o1 = __shfl_xor(g1, off, NW);
            const unsigned long long o2 = __shfl_xor(g2, off, NW);
            p2_merge(g1, g2, o1, o2);
        }
        // ---- decode winners; one s_load_dwordx4 each (wave-uniform) ----
        const int s1i = __builtin_amdgcn_readfirstlane((int)(g1 & 0x3FFFu));
        const int s2i = __builtin_amdgcn_readfirstlane((int)(g2 & 0x3FFFu));
        const float4 w1 = PB[s1i];
        const float4 w2 = PB[s2i];
        // Exact pairing test: t1's update leaves md[t2] unchanged bitwise
        // iff d_frozen(t2,t1) >= md[t2]  (fminf returns md in that case).
        const float v2val = __uint_as_float((unsigned)(g2 >> 32));
        const float d21 = sqd_f32dag(w2.x, w2.y, w2.z, w1.x, w1.y, w1.z);
        const bool paired = (d21 >= v2val) && (v2val > 0.0f) && (m + 1 < M);
        if (t == 0) {
            idx_out[(size_t)b * M + m] = 16383 - (int)((g1 >> 14) & 0x3FFFu);
            if (paired) idx_out[(size_t)b * M + m + 1] = 16383 - (int)((g2 >> 14) & 0x3FFFu);
        }
        s1x = w1.x; s1y = w1.y; s1z = w1.z;
        s2x = w2.x; s2y = w2.y; s2z = w2.z;
        have2 = paired;
        m += paired ? 2 : 1;
        buf ^= 1;
    }
}

// Gather: out = [x[gidx] (BM x 128 f32)] ++ [pos[gidx] (BM x 3 f32)] ++ [batch[gidx] (BM f32)]
__global__ __launch_bounds__(256) void gather_kernel(const float* __restrict__ x,
                                                     const float* __restrict__ pos,
                                                     const int* __restrict__ idx,
                                                     float* __restrict__ out,
                                                     int P, int M, int F, int BM) {
    const int r    = blockIdx.x * 8 + (threadIdx.x >> 5);
    const int lane = threadIdx.x & 31;
    if (r >= BM) return;
    const int b  = r / M;
    const int li = idx[r];
    const size_t g = (size_t)b * P + li;

    const float4* xr   = reinterpret_cast<const float4*>(x + g * (size_t)F);
    float4*       orow = reinterpret_cast<float4*>(out + (size_t)r * F);
    orow[lane] = xr[lane];

    const size_t pos_base   = (size_t)BM * F;
    const size_t batch_base = pos_base + (size_t)BM * 3;
    if (lane < 3)  out[pos_base + (size_t)r * 3 + lane] = pos[g * 3 + lane];
    if (lane == 3) out[batch_base + r] = (float)b;
}

extern "C" void kernel_launch(void* const* d_in, const int* in_sizes, int n_in,
                              void* d_out, int out_size, void* d_ws, size_t ws_size,
                              hipStream_t stream) {
    const float* x   = (const float*)d_in[0];
    const float* pos = (const float*)d_in[1];
    const int N = in_sizes[2];          // 262144
    const int F = in_sizes[0] / N;      // 128
    const int B = 16;
    const int P = N / B;                // 16384
    const int M = P / 4;                // 4096
    const int BM = B * M;               // 65536
    const int PP = B * P;               // 262144

    int* idx_ws = (int*)d_ws;           // BM ints = 256 KB

    // Sorted-cloud scratch (float4 per point = 4 MB) lives in the TAIL of d_out:
    // fully consumed by fps_kernel before gather_kernel overwrites out.
    float* out_f = (float*)d_out;
    float4* pxyz = (float4*)(out_f + (out_size - 4 * PP));

    preprocess_kernel<<<B, FPS_T, 0, stream>>>(pos, pxyz, P);
    fps_kernel<<<B, FPS_T, 0, stream>>>(pos, pxyz, idx_ws, P, M);
    gather_kernel<<<(BM + 7) / 8, 256, 0, stream>>>(x, pos, idx_ws, (float*)d_out, P, M, F, BM);
}

// Round 17
// 8061.112 us; speedup vs baseline: 1.3409x; 1.3409x over previous
//
#include <hip/hip_runtime.h>

#define FPS_T 1024
#define FPS_K 16
#define NW    (FPS_T / 64)   // 16 waves
#define NCELL 512            // 8x8x8 spatial grid

// FROZEN golden arithmetic (verified absmax=0 in R12..R16): f32, LLVM-DAG order
//   d = fma(dz,dz, fma(dx,dx, rn(dy*dy)))
__device__ __forceinline__ float sqd_f32dag(float ax, float ay, float az,
                                            float bx, float by, float bz) {
    const float dx = __fsub_rn(ax, bx);
    const float dy = __fsub_rn(ay, by);
    const float dz = __fsub_rn(az, bz);
    float acc = __fmul_rn(dy, dy);
    acc = __builtin_fmaf(dx, dx, acc);
    acc = __builtin_fmaf(dz, dz, acc);
    return acc;
}

// Counting-sort each cloud by 8x8x8 cell id into float4 {x,y,z, bits(16383-orig)}.
__global__ __launch_bounds__(1024) void preprocess_kernel(const float* __restrict__ pos,
                                                          float4* __restrict__ pxyz,
                                                          int P) {
    const int b = blockIdx.x, t = threadIdx.x;
    const float* posb = pos + (size_t)b * P * 3;
    float4* PB = pxyz + (size_t)b * P;

    __shared__ unsigned hist[NCELL];
    __shared__ unsigned scanb[NCELL];
    __shared__ float s_red[NW][8];

    float x[FPS_K], y[FPS_K], z[FPS_K];
    float lx = 1e30f, ly = 1e30f, lz = 1e30f, hx = -1e30f, hy = -1e30f, hz = -1e30f;
#pragma unroll
    for (int k = 0; k < FPS_K; ++k) {
        const int p = k * FPS_T + t;
        x[k] = posb[p * 3 + 0]; y[k] = posb[p * 3 + 1]; z[k] = posb[p * 3 + 2];
        lx = fminf(lx, x[k]); hx = fmaxf(hx, x[k]);
        ly = fminf(ly, y[k]); hy = fmaxf(hy, y[k]);
        lz = fminf(lz, z[k]); hz = fmaxf(hz, z[k]);
    }
#pragma unroll
    for (int off = 32; off >= 1; off >>= 1) {
        lx = fminf(lx, __shfl_xor(lx, off, 64)); hx = fmaxf(hx, __shfl_xor(hx, off, 64));
        ly = fminf(ly, __shfl_xor(ly, off, 64)); hy = fmaxf(hy, __shfl_xor(hy, off, 64));
        lz = fminf(lz, __shfl_xor(lz, off, 64)); hz = fmaxf(hz, __shfl_xor(hz, off, 64));
    }
    if ((t & 63) == 0) {
        const int w = t >> 6;
        s_red[w][0] = lx; s_red[w][1] = ly; s_red[w][2] = lz;
        s_red[w][3] = hx; s_red[w][4] = hy; s_red[w][5] = hz;
    }
    if (t < NCELL) hist[t] = 0;
    __syncthreads();
    lx = s_red[0][0]; ly = s_red[0][1]; lz = s_red[0][2];
    hx = s_red[0][3]; hy = s_red[0][4]; hz = s_red[0][5];
#pragma unroll
    for (int w = 1; w < NW; ++w) {
        lx = fminf(lx, s_red[w][0]); ly = fminf(ly, s_red[w][1]); lz = fminf(lz, s_red[w][2]);
        hx = fmaxf(hx, s_red[w][3]); hy = fmaxf(hy, s_red[w][4]); hz = fmaxf(hz, s_red[w][5]);
    }
    const float ivx = 8.0f / fmaxf(hx - lx, 1e-20f);
    const float ivy = 8.0f / fmaxf(hy - ly, 1e-20f);
    const float ivz = 8.0f / fmaxf(hz - lz, 1e-20f);

    int cid[FPS_K];
#pragma unroll
    for (int k = 0; k < FPS_K; ++k) {
        int cx = (int)((x[k] - lx) * ivx); cx = cx < 0 ? 0 : (cx > 7 ? 7 : cx);
        int cy = (int)((y[k] - ly) * ivy); cy = cy < 0 ? 0 : (cy > 7 ? 7 : cy);
        int cz = (int)((z[k] - lz) * ivz); cz = cz < 0 ? 0 : (cz > 7 ? 7 : cz);
        cid[k] = (cx << 6) | (cy << 3) | cz;
        atomicAdd(&hist[cid[k]], 1u);
    }
    __syncthreads();
    if (t < NCELL) scanb[t] = hist[t];
    __syncthreads();
    for (int off = 1; off < NCELL; off <<= 1) {
        unsigned add = 0;
        if (t < NCELL && t >= off) add = scanb[t - off];
        __syncthreads();
        if (t < NCELL) scanb[t] += add;
        __syncthreads();
    }
    if (t < NCELL) hist[t] = scanb[t] - hist[t];
    __syncthreads();
#pragma unroll
    for (int k = 0; k < FPS_K; ++k) {
        const int p = k * FPS_T + t;
        const unsigned dst = atomicAdd(&hist[cid[k]], 1u);
        PB[dst] = make_float4(x[k], y[k], z[k], __uint_as_float((unsigned)(16383 - p)));
    }
}

__global__ __launch_bounds__(1024) void fps_kernel(const float* __restrict__ pos,
                                                   const float4* __restrict__ pxyz,
                                                   int* __restrict__ idx_out,
                                                   int P, int M) {
#pragma clang fp contract(off)
    const int b = blockIdx.x, t = threadIdx.x;
    const int lane = t & 63, w = t >> 6;
    const float* posb = pos + (size_t)b * P * 3;
    const float4* PB = pxyz + (size_t)b * P;

    // Per-wave winner slots (double-buffered): value, payload, coords.
    __shared__ float    s_val[2][NW];
    __shared__ unsigned s_pay[2][NW];
    __shared__ float4   s_wpos[2][NW];

    // Thread owns 16 consecutive sorted points: coords/md/payload/bbox in registers.
    float px[FPS_K], py[FPS_K], pz[FPS_K], md[FPS_K];
    unsigned pay[FPS_K];                 // (tor<<14) | sorted_pos  (28 bits)
    const int sp0 = t * FPS_K;
#pragma unroll
    for (int k = 0; k < FPS_K; ++k) {
        const float4 v = PB[sp0 + k];
        px[k] = v.x; py[k] = v.y; pz[k] = v.z;
        pay[k] = (__float_as_uint(v.w) << 14) | (unsigned)(sp0 + k);
        md[k] = __builtin_inff();        // fminf(+inf, d) == d bitwise
    }
    float blx = px[0], bhx = px[0], bly = py[0], bhy = py[0], blz = pz[0], bhz = pz[0];
#pragma unroll
    for (int k = 1; k < FPS_K; ++k) {
        blx = fminf(blx, px[k]); bhx = fmaxf(bhx, px[k]);
        bly = fminf(bly, py[k]); bhy = fmaxf(bhy, py[k]);
        blz = fminf(blz, pz[k]); bhz = fmaxf(bhz, pz[k]);
    }
    if (t == 0) idx_out[(size_t)b * M] = 0;

    // Cached per-thread best (valid while this thread's md is provably unchanged).
    float cval = -1.0f; unsigned cpay = 0u;
    float cbx = 0.f, cby = 0.f, cbz = 0.f;
    bool  owner = false;                 // am I my wave's current winner-owner?
    float thresh = __builtin_inff();
    float sx = posb[0], sy = posb[1], sz = posb[2];

    for (int m = 1; m < M; ++m) {
        const int buf = m & 1;
        // ---- exact bbox skip (R15-verified): skip iff bb >= local_max*(1+2^-14) ----
        const float cx = fminf(fmaxf(sx, blx), bhx);
        const float cy = fminf(fmaxf(sy, bly), bhy);
        const float cz = fminf(fmaxf(sz, blz), bhz);
        const float bb = sqd_f32dag(cx, cy, cz, sx, sy, sz);
        const bool active = bb < thresh;
        if (__ballot(active) != 0ull) {
            if (active) {
                float bval = -1.0f; unsigned bpay = 0u;
                float bx = 0.f, by = 0.f, bz = 0.f;
#pragma unroll
                for (int k = 0; k < FPS_K; ++k) {
                    const float d  = sqd_f32dag(px[k], py[k], pz[k], sx, sy, sz);
                    const float nm = fminf(md[k], d);
                    md[k] = nm;
                    // exact (val, tor) order: pay compare == tor compare (tor unique)
                    const bool better = (nm > bval) || (nm == bval && pay[k] > bpay);
                    if (better) { bval = nm; bpay = pay[k]; bx = px[k]; by = py[k]; bz = pz[k]; }
                }
                cval = bval; cpay = bpay; cbx = bx; cby = by; cbz = bz;
                thresh = bval * 1.00006104f;   // *(1+2^-14)
            }
            // ---- 32-bit value butterfly (cheap) + ballot owner-resolve ----
            float wv = cval;
#pragma unroll
            for (int off = 32; off >= 1; off >>= 1)
                wv = fmaxf(wv, __shfl_xor(wv, off, 64));
            const unsigned long long mask = __ballot(cval == wv);
            if (__popcll(mask) == 1) {
                owner = (mask >> lane) & 1ull;
            } else {
                // rare exact value-tie: full u64 (val,tor) butterfly — first-occurrence exact
                unsigned long long kk = ((unsigned long long)__float_as_uint(cval) << 32) | cpay;
                unsigned long long wm = kk;
#pragma unroll
                for (int off = 32; off >= 1; off >>= 1) {
                    const unsigned long long o = __shfl_xor(wm, off, 64);
                    if (o > wm) wm = o;
                }
                owner = (kk == wm);
            }
        }
        // Owner (persisted across skipped iterations) deposits its wave's winner.
        if (owner) {
            s_val[buf][w]  = cval;
            s_pay[buf][w]  = cpay;
            s_wpos[buf][w] = make_float4(cbx, cby, cbz, 0.0f);
        }
        __syncthreads();
        // ---- cross-wave tree over 16 slots (u64 exact) ----
        const int sl = lane & (NW - 1);
        unsigned long long g = ((unsigned long long)__float_as_uint(s_val[buf][sl]) << 32)
                             | s_pay[buf][sl];
#pragma unroll
        for (int off = NW / 2; off >= 1; off >>= 1) {
            const unsigned long long o = __shfl_xor(g, off, NW);
            if (o > g) g = o;
        }
        const unsigned gp = (unsigned)g;
        // rotate the global-store across waves: vmcnt drain never hits one wave twice
        if (t == ((m & 15) << 6)) idx_out[(size_t)b * M + m] = 16383 - (int)((gp >> 14) & 0x3FFFu);
        // winner coords: LDS broadcast (wave id = sorted_pos >> 10)
        const float4 wp = s_wpos[buf][(gp & 0x3FFFu) >> 10];
        sx = wp.x; sy = wp.y; sz = wp.z;
    }
}

// Gather: out = [x[gidx] (BM x 128 f32)] ++ [pos[gidx] (BM x 3 f32)] ++ [batch[gidx] (BM f32)]
__global__ __launch_bounds__(256) void gather_kernel(const float* __restrict__ x,
                                                     const float* __restrict__ pos,
                                                     const int* __restrict__ idx,
                                                     float* __restrict__ out,
                                                     int P, int M, int F, int BM) {
    const int r    = blockIdx.x * 8 + (threadIdx.x >> 5);
    const int lane = threadIdx.x & 31;
    if (r >= BM) return;
    const int b  = r / M;
    const int li = idx[r];
    const size_t g = (size_t)b * P + li;

    const float4* xr   = reinterpret_cast<const float4*>(x + g * (size_t)F);
    float4*       orow = reinterpret_cast<float4*>(out + (size_t)r * F);
    orow[lane] = xr[lane];

    const size_t pos_base   = (size_t)BM * F;
    const size_t batch_base = pos_base + (size_t)BM * 3;
    if (lane < 3)  out[pos_base + (size_t)r * 3 + lane] = pos[g * 3 + lane];
    if (lane == 3) out[batch_base + r] = (float)b;
}

extern "C" void kernel_launch(void* const* d_in, const int* in_sizes, int n_in,
                              void* d_out, int out_size, void* d_ws, size_t ws_size,
                              hipStream_t stream) {
    const float* x   = (const float*)d_in[0];
    const float* pos = (const float*)d_in[1];
    const int N = in_sizes[2];          // 262144
    const int F = in_sizes[0] / N;      // 128
    const int B = 16;
    const int P = N / B;                // 16384
    const int M = P / 4;                // 4096
    const int BM = B * M;               // 65536
    const int PP = B * P;               // 262144

    int* idx_ws = (int*)d_ws;           // BM ints = 256 KB

    // Sorted-cloud scratch (float4/point = 4 MB) in the TAIL of d_out: consumed
    // by fps_kernel strictly before gather_kernel overwrites out.
    float* out_f = (float*)d_out;
    float4* pxyz = (float4*)(out_f + (out_size - 4 * PP));

    preprocess_kernel<<<B, FPS_T, 0, stream>>>(pos, pxyz, P);
    fps_kernel<<<B, FPS_T, 0, stream>>>(pos, pxyz, idx_ws, P, M);
    gather_kernel<<<(BM + 7) / 8, 256, 0, stream>>>(x, pos, idx_ws, (float*)d_out, P, M, F, BM);
}